// Round 2
// baseline (484.801 us; speedup 1.0000x reference)
//
#include <hip/hip_runtime.h>

typedef float f4 __attribute__((ext_vector_type(4)));

#define Gn 4
#define Bn 2
#define Tn 32
#define Cn 128
#define Hn 64
#define Wn 64
#define HC 16
#define WC 16
#define HW (Hn * Wn)

// block = (g, b, h, whalf, qhalf); 256 threads
// thread tile = 4q x 4c x 4w; cslot covers all 32 c of the group in one pass
__global__ __launch_bounds__(256, 4)
void temporal_agg_kernel(const float* __restrict__ x,
                         const float* __restrict__ attn,
                         float* __restrict__ out) {
    const int bid   = blockIdx.x;
    const int qhalf = bid & 1;
    const int whalf = (bid >> 1) & 1;
    const int h     = (bid >> 2) & 63;
    const int b     = (bid >> 8) & 1;
    const int g     = bid >> 9;
    const int tid   = threadIdx.x;

    // half-pixel h interpolation: src = 0.25*h - 0.375
    const float chf = 0.25f * (float)h - 0.375f;
    const float h0f = floorf(chf);
    const float fh  = chf - h0f;
    int h0 = (int)h0f;
    int h1 = h0 + 1;
    h0 = min(max(h0, 0), HC - 1);
    h1 = min(max(h1, 0), HC - 1);

    // Ah[k][j][ql]: h-lerped coarse attn, j = coarse w col (10 incl. halo),
    // ql = local q (16), padded 16->20 (80 B row: 16B-aligned for b128)
    __shared__ float Ah[Tn][10][20];   // 25.6 KB

    const int wcb = whalf * 8 - 1;     // coarse col of j=0 (clamped dup at edge)
    const int qb  = qhalf * 16;
    const float* abase = attn + (size_t)(g * Bn + b) * (Tn * Tn * HC * WC);

    // ---- phase 1: global -> LDS, h-lerp, transpose to q-fast (f4 loads) ----
    #pragma unroll
    for (int i = 0; i < 8; ++i) {
        int idx = tid + 256 * i;       // [0, 2048)
        int c4 = idx & 3;
        int k  = (idx >> 2) & 31;
        int ql = idx >> 7;             // 0..15
        const float* p = abase + (size_t)((qb + ql) * Tn + k) * (HC * WC);
        f4 v0 = *(const f4*)(p + h0 * WC + 4 * c4);
        f4 v1 = *(const f4*)(p + h1 * WC + 4 * c4);
        f4 ah = v0 + fh * (v1 - v0);
        #pragma unroll
        for (int e = 0; e < 4; ++e) {
            int wc = 4 * c4 + e;
            int j = wc - wcb;
            if (j >= 0 && j < 10) Ah[k][j][ql] = ah[e];
            if (whalf == 0 && wc == 0)  Ah[k][0][ql] = ah[e];  // clamp col -1 -> 0
            if (whalf == 1 && wc == 15) Ah[k][9][ql] = ah[e];  // clamp col 16 -> 15
        }
    }
    __syncthreads();

    // ---- phase 2: per-pixel temporal matmul, x prefetched 1 k ahead ----
    const int qslot = tid & 3;          // 4 * 4 = 16 q
    const int wl    = (tid >> 2) & 7;   // 8 * 4 = 32 fine w in this half
    const int cslot = tid >> 5;         // 8 * 4 = 32 c (full group)
    const int ql0   = qslot * 4;
    const int wfine = whalf * 32 + wl * 4;
    const int off_hw = h * Wn + wfine;
    const int cbase  = g * 32 + cslot * 4;

    const float* xb = x + (size_t)b * (Tn * Cn * HW)
                        + (size_t)cbase * HW + off_hw;
    const size_t kstride = (size_t)Cn * HW;

    f4 acc[4][4];
    #pragma unroll
    for (int qq = 0; qq < 4; ++qq)
        #pragma unroll
        for (int cc = 0; cc < 4; ++cc)
            acc[qq][cc] = (f4)0.0f;

    f4 xv[4];
    #pragma unroll
    for (int cc = 0; cc < 4; ++cc)
        xv[cc] = *(const f4*)(xb + cc * HW);

#define COMPUTE(kk)                                                     \
    do {                                                                \
        f4 t0 = *(const f4*)&Ah[kk][wl    ][ql0];                       \
        f4 t1 = *(const f4*)&Ah[kk][wl + 1][ql0];                       \
        f4 t2 = *(const f4*)&Ah[kk][wl + 2][ql0];                       \
        _Pragma("unroll")                                               \
        for (int qq = 0; qq < 4; ++qq) {                                \
            f4 a;                                                       \
            a.x = 0.375f * t0[qq] + 0.625f * t1[qq];                    \
            a.y = 0.125f * t0[qq] + 0.875f * t1[qq];                    \
            a.z = 0.875f * t1[qq] + 0.125f * t2[qq];                    \
            a.w = 0.625f * t1[qq] + 0.375f * t2[qq];                    \
            _Pragma("unroll")                                           \
            for (int cc = 0; cc < 4; ++cc)                              \
                acc[qq][cc] += a * xv[cc];                              \
        }                                                               \
    } while (0)

    #pragma unroll 4
    for (int k = 0; k < Tn - 1; ++k) {
        const float* xn_p = xb + (size_t)(k + 1) * kstride;
        f4 xn[4];
        #pragma unroll
        for (int cc = 0; cc < 4; ++cc)
            xn[cc] = *(const f4*)(xn_p + cc * HW);
        COMPUTE(k);
        #pragma unroll
        for (int cc = 0; cc < 4; ++cc)
            xv[cc] = xn[cc];
    }
    COMPUTE(Tn - 1);
#undef COMPUTE

    #pragma unroll
    for (int qq = 0; qq < 4; ++qq) {
        const int q = qb + ql0 + qq;
        float* ob = out + ((size_t)(b * Tn + q) * Cn + cbase) * HW + off_hw;
        #pragma unroll
        for (int cc = 0; cc < 4; ++cc)
            *(f4*)(ob + cc * HW) = acc[qq][cc];
    }
}

extern "C" void kernel_launch(void* const* d_in, const int* in_sizes, int n_in,
                              void* d_out, int out_size, void* d_ws, size_t ws_size,
                              hipStream_t stream) {
    const float* x    = (const float*)d_in[0];
    const float* attn = (const float*)d_in[1];
    float* out        = (float*)d_out;
    temporal_agg_kernel<<<dim3(Gn * Bn * Hn * 2 * 2), dim3(256), 0, stream>>>(x, attn, out);
}